// Round 12
// baseline (202.729 us; speedup 1.0000x reference)
//
#include <hip/hip_runtime.h>

#define BC 4096      // rows of hidden_current
#define BP 8192      // rows of hidden_previous
#define D  768
#define KNB 5
#define TOPK 6
#define NT (BP / 128)   // 64 column tiles of the similarity matrix
// tile grid: 1024 rectangular (ci>=32) + 528 triangular (ri<=ci<32); the
// symmetric square's lower triangle is harvested from the upper via col-scan.
#define NBLK 1552

typedef __bf16 bf16x8 __attribute__((ext_vector_type(8)));
typedef float  f32x4  __attribute__((ext_vector_type(4)));

__device__ __forceinline__ unsigned short f2bf(float f) {
    unsigned int u = __float_as_uint(f);
    u += 0x7fffu + ((u >> 16) & 1u);          // round-to-nearest-even
    return (unsigned short)(u >> 16);
}

__device__ __forceinline__ void gload16(const void* g, void* l) {
    __builtin_amdgcn_global_load_lds(
        (const __attribute__((address_space(1))) unsigned int*)g,
        (__attribute__((address_space(3))) unsigned int*)l, 16, 0, 0);
}

// Branchless insertion network, STATIC indices only (r6 lesson: runtime-indexed
// private arrays -> scratch). Strict >: ties keep the incumbent (earlier j),
// matching reference sequential j-ascending top_k.
__device__ __forceinline__ void topk_insert(float v, int j, float* bv, int* bj) {
    #pragma unroll
    for (int q = TOPK - 1; q >= 1; q--) {
        bool up   = v > bv[q - 1];
        bool here = (v > bv[q]) && !up;
        bv[q] = up ? bv[q - 1] : (here ? v : bv[q]);
        bj[q] = up ? bj[q - 1] : (here ? j : bj[q]);
    }
    if (v > bv[0]) { bv[0] = v; bj[0] = j; }
}

// ---------------- fused normalize: hp -> bf16 ranking copy, hc -> fp32 + sq ------
// hpnb is PRE-SWIZZLED: element e of row r stored at e ^ ((r&7)<<3) so monotone
// global_load_lds lands the XOR-swizzled LDS layout for free -> conflict-free
// fragment reads (r10 win: conflicts 2.0e7 -> 1.1e6). Also zeroes out[0].
__global__ __launch_bounds__(256) void k_norm(const float* __restrict__ hp,
                                              const float* __restrict__ hc,
                                              unsigned short* __restrict__ hpnb,
                                              float* __restrict__ hcn,
                                              float* __restrict__ sqout,
                                              float* __restrict__ out) {
    int b = blockIdx.x;
    int t = threadIdx.x;
    if (b == 0 && t == 0) out[0] = 0.0f;
    bool isP = (b < BP);
    int row = isP ? b : (b - BP);
    const float* xr = (isP ? hp : hc) + (size_t)row * D;
    float v0 = xr[t], v1 = xr[t + 256], v2 = xr[t + 512];
    float s = v0 * v0 + v1 * v1 + v2 * v2;
    #pragma unroll
    for (int off = 32; off; off >>= 1) s += __shfl_xor(s, off, 64);
    __shared__ float wsum[4];
    if ((t & 63) == 0) wsum[t >> 6] = s;
    __syncthreads();
    float tot = wsum[0] + wsum[1] + wsum[2] + wsum[3];
    float rinv = 1.0f / fmaxf(sqrtf(tot), 1e-12f);
    if (isP) {
        unsigned short* yr = hpnb + (size_t)row * D;
        int rx = (row & 7) << 3;                       // chunk swizzle (bits 3..5)
        yr[t ^ rx]         = f2bf(v0 * rinv);
        yr[(t + 256) ^ rx] = f2bf(v1 * rinv);
        yr[(t + 512) ^ rx] = f2bf(v2 * rinv);
    } else {
        float* yr = hcn + (size_t)row * D;
        yr[t] = v0 * rinv; yr[t + 256] = v1 * rinv; yr[t + 512] = v2 * rinv;
        if (t == 0) sqout[row] = tot * rinv * rinv;
    }
}

// ---------------- bf16 MFMA similarity tile + fused top-6, SYMMETRY-AWARE -------
// S = hp.hp^T is symmetric: tiles (ri,ci) and (ci,ri) with ri,ci<32 hold
// bitwise-identical scores (same k-order). Compute only ri<=ci; for ri<ci also
// run a COLUMN-scan epilogue that yields cand[rows of ci-block][cb=ri].
// 1552 blocks vs 2048: -24.2% MFMA + staging. launch_bounds(256,3): r11's
// (256,4) pinned regs at the live set and spilled (+10MB WRITE) with no
// occupancy gain.
__global__ __launch_bounds__(256, 3) void k_simtop(const unsigned short* __restrict__ hp,
                                                   float* __restrict__ candv,
                                                   int* __restrict__ candi) {
    __shared__ char smem[32768];
    unsigned short* sA = (unsigned short*)smem;          // [128 rows][64 k] swizzled
    unsigned short* sB = sA + 128 * 64;
    float* sS = (float*)smem;                            // [128][33] score buf (alias)
    float* mv = (float*)(smem + 17408);                  // [128][6] partner vals
    int*   mj = (int*)(smem + 17408 + 3072);             // [128][6] partner idx

    const int t = threadIdx.x;
    const int l = t & 63;
    const int w = t >> 6;
    const int l15 = l & 15, quad = l >> 4;
    const int wr = w >> 1, wc = w & 1;

    // block -> (ri, ci) tile mapping
    int ri, ci; bool tri;
    {
        int idx = blockIdx.x;
        if (idx < 1024) { ri = idx >> 5; ci = 32 + (idx & 31); tri = false; }
        else {
            int r = idx - 1024, a = 0;
            while (r >= 32 - a) { r -= 32 - a; a++; }    // unrank upper triangle
            ri = a; ci = a + r; tri = (ri != ci);        // diagonal: row-scan only
        }
    }

    // per-lane global source: row group w*32 + p*8 + (l>>3), chunk l&7 (monotone)
    const int srow = l >> 3, sch = l & 7;
    const unsigned short* Ag = hp + (size_t)(ri * 128 + w * 32 + srow) * D + sch * 8;
    const unsigned short* Bg = hp + (size_t)(ci * 128 + w * 32 + srow) * D + sch * 8;
    unsigned short* la = sA + (w * 32) * 64;             // wave-uniform LDS bases
    unsigned short* lb = sB + (w * 32) * 64;

    f32x4 acc[4][4];
    #pragma unroll
    for (int i = 0; i < 4; i++)
        #pragma unroll
        for (int j = 0; j < 4; j++) acc[i][j] = (f32x4){0.f, 0.f, 0.f, 0.f};

    // fragment LDS chunk offsets (lane-constant, conflict-free): original
    // k-chunk q of row r sits at LDS pos q^(r&7); frag rows have r&7 == l15&7.
    const int x7  = l15 & 7;
    const int ch0 = (quad ^ x7) * 16;
    const int ch1 = ((quad + 4) ^ x7) * 16;

    for (int kk = 0; kk < D; kk += 64) {
        __syncthreads();                                 // prev iter's LDS reads done
        #pragma unroll
        for (int p = 0; p < 4; p++) {
            gload16(Ag + (size_t)(p * 8) * D + kk, la + (p * 8) * 64);
            gload16(Bg + (size_t)(p * 8) * D + kk, lb + (p * 8) * 64);
        }
        __syncthreads();                                 // vmcnt drain + tile ready
        #pragma unroll
        for (int ks = 0; ks < 2; ks++) {
            const int ch = ks ? ch1 : ch0;
            bf16x8 af[4], bfr[4];
            #pragma unroll
            for (int mi = 0; mi < 4; mi++)
                af[mi] = *(const bf16x8*)((const char*)sA + (wr * 64 + mi * 16 + l15) * 128 + ch);
            #pragma unroll
            for (int ni = 0; ni < 4; ni++)
                bfr[ni] = *(const bf16x8*)((const char*)sB + (wc * 64 + ni * 16 + l15) * 128 + ch);
            #pragma unroll
            for (int mi = 0; mi < 4; mi++)
                #pragma unroll
                for (int ni = 0; ni < 4; ni++)
                    acc[mi][ni] = __builtin_amdgcn_mfma_f32_16x16x32_bf16(af[mi], bfr[ni], acc[mi][ni], 0, 0, 0);
        }
    }

    // ---------- row-scan epilogue: 4 dump phases of 32 cols ----------
    float bv[TOPK]; int bj[TOPK];
    #pragma unroll
    for (int s = 0; s < TOPK; s++) { bv[s] = -1e30f; bj[s] = 0x7fffffff; }

    const int erow = t & 127, scb = (t >> 7) * 16;
    #pragma unroll
    for (int p = 0; p < 4; p++) {
        __syncthreads();
        if (wc == (p >> 1)) {
            const int ni0 = (p & 1) * 2;
            #pragma unroll
            for (int mi = 0; mi < 4; mi++)
                #pragma unroll
                for (int n2 = 0; n2 < 2; n2++) {
                    int colb = n2 * 16 + l15;
                    int rowb = wr * 64 + mi * 16 + quad * 4;
                    f32x4 v = acc[mi][ni0 + n2];
                    #pragma unroll
                    for (int r = 0; r < 4; r++) sS[(rowb + r) * 33 + colb] = v[r];
                }
        }
        __syncthreads();
        int jbase = ci * 128 + p * 32 + scb;
        for (int c = 0; c < 16; c++) {
            float v = sS[erow * 33 + scb + c];
            if (v > bv[TOPK - 1]) topk_insert(v, jbase + c, bv, bj);
        }
    }
    __syncthreads();
    if (t >= 128) {
        #pragma unroll
        for (int s = 0; s < TOPK; s++) { mv[(t - 128) * TOPK + s] = bv[s]; mj[(t - 128) * TOPK + s] = bj[s]; }
    }
    __syncthreads();
    if (t < 128) {
        #pragma unroll
        for (int s0 = 0; s0 < TOPK; s0++) {
            float v = mv[t * TOPK + s0];
            if (v > bv[TOPK - 1]) topk_insert(v, mj[t * TOPK + s0], bv, bj);
        }
        size_t o = ((size_t)(ri * 128 + t) * NT + ci) * TOPK;
        #pragma unroll
        for (int s = 0; s < TOPK; s++) { candv[o + s] = bv[s]; candi[o + s] = bj[s]; }
    }

    // ---------- column-scan epilogue (triangular tiles only) ----------
    // By symmetry, column co of this tile = row ci*128+co vs columns ri*128+a.
    // Transposed dump in 4 phases over original-row chunks of 32; scanners walk
    // a ascending (j ascending) -> same tie semantics as row-scan.
    if (tri) {
        #pragma unroll
        for (int s = 0; s < TOPK; s++) { bv[s] = -1e30f; bj[s] = 0x7fffffff; }
        #pragma unroll
        for (int p = 0; p < 4; p++) {
            __syncthreads();
            if (wr == (p >> 1)) {
                const int mi0 = (p & 1) * 2;
                #pragma unroll
                for (int m2 = 0; m2 < 2; m2++)
                    #pragma unroll
                    for (int ni = 0; ni < 4; ni++) {
                        int co = wc * 64 + ni * 16 + l15;          // original col
                        int lr = m2 * 16 + quad * 4;               // row within chunk
                        f32x4 v = acc[mi0 + m2][ni];
                        #pragma unroll
                        for (int r = 0; r < 4; r++) sS[co * 33 + lr + r] = v[r];
                    }
            }
            __syncthreads();
            int jbase = ri * 128 + p * 32 + scb;
            for (int c = 0; c < 16; c++) {
                float v = sS[erow * 33 + scb + c];
                if (v > bv[TOPK - 1]) topk_insert(v, jbase + c, bv, bj);
            }
        }
        __syncthreads();
        if (t >= 128) {
            #pragma unroll
            for (int s = 0; s < TOPK; s++) { mv[(t - 128) * TOPK + s] = bv[s]; mj[(t - 128) * TOPK + s] = bj[s]; }
        }
        __syncthreads();
        if (t < 128) {
            #pragma unroll
            for (int s0 = 0; s0 < TOPK; s0++) {
                float v = mv[t * TOPK + s0];
                if (v > bv[TOPK - 1]) topk_insert(v, mj[t * TOPK + s0], bv, bj);
            }
            size_t o = ((size_t)(ci * 128 + t) * NT + ri) * TOPK;
            #pragma unroll
            for (int s = 0; s < TOPK; s++) { candv[o + s] = bv[s]; candi[o + s] = bj[s]; }
        }
    }
}

// ------- fused merge (wave-parallel) + sparse loss + global atomic accumulate ----
// 256-thread blocks, 4 rows/block (wave per row). Per wave: 6-round xor merge of
// the 64 per-tile sorted top-6 lists (low-lane base preserves earlier-j ties),
// then deferred-reduction loss with ONE wave reduction. Clamp dropped (d2 =
// sqi+sqj-2dot, dot <= ~0.25 for distinct normalized rows -> max(.,0) dead).
__global__ __launch_bounds__(256) void k_mergeloss(const float* __restrict__ candv,
                                                   const int* __restrict__ candi,
                                                   const float* __restrict__ hcn,
                                                   const float* __restrict__ sq,
                                                   const int* __restrict__ labp,
                                                   float* __restrict__ out) {
    __shared__ float bsum[4];
    const int w = threadIdx.x >> 6, lane = threadIdx.x & 63;
    const int i = blockIdx.x * 4 + w;

    const float* cv = candv + ((size_t)i * NT + lane) * TOPK;
    const int*   cj = candi + ((size_t)i * NT + lane) * TOPK;
    float bv[TOPK]; int bj[TOPK];
    #pragma unroll
    for (int s = 0; s < TOPK; s++) { bv[s] = cv[s]; bj[s] = cj[s]; }

    #pragma unroll
    for (int off = 1; off < 64; off <<= 1) {
        float pv[TOPK]; int pj[TOPK];
        #pragma unroll
        for (int s = 0; s < TOPK; s++) {
            pv[s] = __shfl_xor(bv[s], off, 64);
            pj[s] = __shfl_xor(bj[s], off, 64);
        }
        bool ilow = (lane & off) == 0;
        float av[TOPK], iv[TOPK]; int aj[TOPK], ij[TOPK];
        #pragma unroll
        for (int s = 0; s < TOPK; s++) {
            av[s] = ilow ? bv[s] : pv[s];  aj[s] = ilow ? bj[s] : pj[s];
            iv[s] = ilow ? pv[s] : bv[s];  ij[s] = ilow ? pj[s] : bj[s];
        }
        #pragma unroll
        for (int s = 0; s < TOPK; s++)
            if (iv[s] > av[TOPK - 1]) topk_insert(iv[s], ij[s], av, aj);
        #pragma unroll
        for (int s = 0; s < TOPK; s++) { bv[s] = av[s]; bj[s] = aj[s]; }
    }

    // loss: ranks 1..5 (rank 0 is self). Deferred reduction.
    const float* hi = hcn + (size_t)i * D;
    float4 h0 = *(const float4*)(hi + lane * 4);
    float4 h1 = *(const float4*)(hi + lane * 4 + 256);
    float4 h2 = *(const float4*)(hi + lane * 4 + 512);
    float sqi = sq[i];
    int li = labp[i];
    float part = 0.f;
    float base = 0.f;
    #pragma unroll
    for (int s = 1; s <= KNB; s++) {
        int j = bj[s];
        if (j >= BC) continue;
        const float* hj = hcn + (size_t)j * D;
        float4 g0 = *(const float4*)(hj + lane * 4);
        float4 g1 = *(const float4*)(hj + lane * 4 + 256);
        float4 g2 = *(const float4*)(hj + lane * 4 + 512);
        float d = h0.x * g0.x + h0.y * g0.y + h0.z * g0.z + h0.w * g0.w
                + h1.x * g1.x + h1.y * g1.y + h1.z * g1.z + h1.w * g1.w
                + h2.x * g2.x + h2.y * g2.y + h2.z * g2.z + h2.w * g2.w;
        float e = (li == labp[j]) ? 1.0f : -1.0f;
        part += e * (-2.0f) * d;
        if (lane == 0) base += e * (sqi + sq[j]);
    }
    part += base;
    #pragma unroll
    for (int off = 32; off; off >>= 1) part += __shfl_xor(part, off, 64);
    if (lane == 0) bsum[w] = part;
    __syncthreads();
    if (threadIdx.x == 0) {
        float s = bsum[0] + bsum[1] + bsum[2] + bsum[3];
        unsafeAtomicAdd(out, 0.5f * s / ((float)BC * (float)BC));
    }
}

extern "C" void kernel_launch(void* const* d_in, const int* in_sizes, int n_in,
                              void* d_out, int out_size, void* d_ws, size_t ws_size,
                              hipStream_t stream) {
    const float* hc   = (const float*)d_in[0];  // hidden_current  (4096,768)
    const float* hp   = (const float*)d_in[1];  // hidden_previous (8192,768)
    const int*   labp = (const int*)d_in[3];    // labels_previous (8192,)
    float* out = (float*)d_out;

    // workspace layout (~38 MB)
    unsigned short* hpnb = (unsigned short*)d_ws;          // BP*D bf16 (pre-swizzled)
    float* hcn  = (float*)(hpnb + (size_t)BP * D);         // BC*D f32
    float* sq   = hcn + (size_t)BC * D;                    // BC
    float* candv = sq + BC;                                // BC*NT*TOPK
    int*   candi = (int*)(candv + (size_t)BC * NT * TOPK); // BC*NT*TOPK

    k_norm<<<dim3(BP + BC), dim3(256), 0, stream>>>(hp, hc, hpnb, hcn, sq, out);
    k_simtop<<<dim3(NBLK), dim3(256), 0, stream>>>(hpnb, candv, candi);
    k_mergeloss<<<dim3(BC / 4), dim3(256), 0, stream>>>(candv, candi, hcn, sq, labp, out);
}

// Round 13
// 190.090 us; speedup vs baseline: 1.0665x; 1.0665x over previous
//
#include <hip/hip_runtime.h>

#define BC 4096      // rows of hidden_current
#define BP 8192      // rows of hidden_previous
#define D  768
#define KNB 5
#define TOPK 6
#define NT (BP / 128)   // 64 column tiles of the similarity matrix
// tile grid: 528 triangular (ri<=ci<32, heavy: dual epilogue) FIRST, then 1024
// rectangular (ci>=32). r12 lesson: heavy blocks last = ragged tail (occ 22%).
#define NTRI 528
#define NBLK 1552

typedef __bf16 bf16x8 __attribute__((ext_vector_type(8)));
typedef float  f32x4  __attribute__((ext_vector_type(4)));

__device__ __forceinline__ unsigned short f2bf(float f) {
    unsigned int u = __float_as_uint(f);
    u += 0x7fffu + ((u >> 16) & 1u);          // round-to-nearest-even
    return (unsigned short)(u >> 16);
}

__device__ __forceinline__ void gload16(const void* g, void* l) {
    __builtin_amdgcn_global_load_lds(
        (const __attribute__((address_space(1))) unsigned int*)g,
        (__attribute__((address_space(3))) unsigned int*)l, 16, 0, 0);
}

// Branchless insertion network, STATIC indices only (r6 lesson: runtime-indexed
// private arrays -> scratch). Strict >: ties keep the incumbent (earlier j),
// matching reference sequential j-ascending top_k.
__device__ __forceinline__ void topk_insert(float v, int j, float* bv, int* bj) {
    #pragma unroll
    for (int q = TOPK - 1; q >= 1; q--) {
        bool up   = v > bv[q - 1];
        bool here = (v > bv[q]) && !up;
        bv[q] = up ? bv[q - 1] : (here ? v : bv[q]);
        bj[q] = up ? bj[q - 1] : (here ? j : bj[q]);
    }
    if (v > bv[0]) { bv[0] = v; bj[0] = j; }
}

// ---------------- fused normalize: hp -> bf16 ranking copy, hc -> fp32 + sq ------
// hpnb is PRE-SWIZZLED: element e of row r stored at e ^ ((r&7)<<3) so monotone
// global_load_lds lands the XOR-swizzled LDS layout for free -> conflict-free
// fragment reads (r10 win: conflicts 2.0e7 -> 1.1e6). Also zeroes out[0].
__global__ __launch_bounds__(256) void k_norm(const float* __restrict__ hp,
                                              const float* __restrict__ hc,
                                              unsigned short* __restrict__ hpnb,
                                              float* __restrict__ hcn,
                                              float* __restrict__ sqout,
                                              float* __restrict__ out) {
    int b = blockIdx.x;
    int t = threadIdx.x;
    if (b == 0 && t == 0) out[0] = 0.0f;
    bool isP = (b < BP);
    int row = isP ? b : (b - BP);
    const float* xr = (isP ? hp : hc) + (size_t)row * D;
    float v0 = xr[t], v1 = xr[t + 256], v2 = xr[t + 512];
    float s = v0 * v0 + v1 * v1 + v2 * v2;
    #pragma unroll
    for (int off = 32; off; off >>= 1) s += __shfl_xor(s, off, 64);
    __shared__ float wsum[4];
    if ((t & 63) == 0) wsum[t >> 6] = s;
    __syncthreads();
    float tot = wsum[0] + wsum[1] + wsum[2] + wsum[3];
    float rinv = 1.0f / fmaxf(sqrtf(tot), 1e-12f);
    if (isP) {
        unsigned short* yr = hpnb + (size_t)row * D;
        int rx = (row & 7) << 3;                       // chunk swizzle (bits 3..5)
        yr[t ^ rx]         = f2bf(v0 * rinv);
        yr[(t + 256) ^ rx] = f2bf(v1 * rinv);
        yr[(t + 512) ^ rx] = f2bf(v2 * rinv);
    } else {
        float* yr = hcn + (size_t)row * D;
        yr[t] = v0 * rinv; yr[t + 256] = v1 * rinv; yr[t + 512] = v2 * rinv;
        if (t == 0) sqout[row] = tot * rinv * rinv;
    }
}

// ---------------- bf16 MFMA similarity tile + fused top-6, SYMMETRY-AWARE -------
// S = hp.hp^T is symmetric: tiles (ri,ci), ri,ci<32 are bitwise-symmetric.
// Compute only ri<=ci; ri<ci tiles also run a COLUMN-scan epilogue yielding
// cand[rows of ci-block][cb=ri]. 1552 blocks vs 2048 = -24% MFMA + staging.
// Triangular (heavy) blocks dispatch FIRST so their extra epilogue overlaps
// the rect bulk instead of forming the tail (r12 regression fix).
__global__ __launch_bounds__(256, 3) void k_simtop(const unsigned short* __restrict__ hp,
                                                   float* __restrict__ candv,
                                                   int* __restrict__ candi) {
    __shared__ char smem[32768];
    unsigned short* sA = (unsigned short*)smem;          // [128 rows][64 k] swizzled
    unsigned short* sB = sA + 128 * 64;
    float* sS = (float*)smem;                            // [128][33] score buf (alias)
    float* mv = (float*)(smem + 17408);                  // [128][6] partner vals
    int*   mj = (int*)(smem + 17408 + 3072);             // [128][6] partner idx

    const int t = threadIdx.x;
    const int l = t & 63;
    const int w = t >> 6;
    const int l15 = l & 15, quad = l >> 4;
    const int wr = w >> 1, wc = w & 1;

    // block -> (ri, ci): tri tiles first (closed-form unrank), rect after
    int ri, ci; bool tri;
    {
        int idx = blockIdx.x;
        if (idx < NTRI) {
            int r = idx;
            int a = (int)((65.0f - sqrtf(4225.0f - 8.0f * (float)r)) * 0.5f);
            a = a < 0 ? 0 : (a > 31 ? 31 : a);
            while (a > 0 && a * (65 - a) / 2 > r) a--;            // fixup (<=1 iter)
            while (a < 31 && (a + 1) * (64 - a) / 2 <= r) a++;    // off(a+1)=(a+1)(65-(a+1))/2
            ri = a; ci = a + (r - a * (65 - a) / 2);
            tri = (ri != ci);                                     // diagonal: row-scan only
        } else {
            int idx2 = idx - NTRI;
            ri = idx2 >> 5; ci = 32 + (idx2 & 31); tri = false;
        }
    }

    // per-lane global source: row group w*32 + p*8 + (l>>3), chunk l&7 (monotone)
    const int srow = l >> 3, sch = l & 7;
    const unsigned short* Ag = hp + (size_t)(ri * 128 + w * 32 + srow) * D + sch * 8;
    const unsigned short* Bg = hp + (size_t)(ci * 128 + w * 32 + srow) * D + sch * 8;
    unsigned short* la = sA + (w * 32) * 64;             // wave-uniform LDS bases
    unsigned short* lb = sB + (w * 32) * 64;

    f32x4 acc[4][4];
    #pragma unroll
    for (int i = 0; i < 4; i++)
        #pragma unroll
        for (int j = 0; j < 4; j++) acc[i][j] = (f32x4){0.f, 0.f, 0.f, 0.f};

    // fragment LDS chunk offsets (lane-constant, conflict-free): original
    // k-chunk q of row r sits at LDS pos q^(r&7); frag rows have r&7 == l15&7.
    const int x7  = l15 & 7;
    const int ch0 = (quad ^ x7) * 16;
    const int ch1 = ((quad + 4) ^ x7) * 16;

    for (int kk = 0; kk < D; kk += 64) {
        __syncthreads();                                 // prev iter's LDS reads done
        #pragma unroll
        for (int p = 0; p < 4; p++) {
            gload16(Ag + (size_t)(p * 8) * D + kk, la + (p * 8) * 64);
            gload16(Bg + (size_t)(p * 8) * D + kk, lb + (p * 8) * 64);
        }
        __syncthreads();                                 // vmcnt drain + tile ready
        #pragma unroll
        for (int ks = 0; ks < 2; ks++) {
            const int ch = ks ? ch1 : ch0;
            bf16x8 af[4], bfr[4];
            #pragma unroll
            for (int mi = 0; mi < 4; mi++)
                af[mi] = *(const bf16x8*)((const char*)sA + (wr * 64 + mi * 16 + l15) * 128 + ch);
            #pragma unroll
            for (int ni = 0; ni < 4; ni++)
                bfr[ni] = *(const bf16x8*)((const char*)sB + (wc * 64 + ni * 16 + l15) * 128 + ch);
            #pragma unroll
            for (int mi = 0; mi < 4; mi++)
                #pragma unroll
                for (int ni = 0; ni < 4; ni++)
                    acc[mi][ni] = __builtin_amdgcn_mfma_f32_16x16x32_bf16(af[mi], bfr[ni], acc[mi][ni], 0, 0, 0);
        }
    }

    // ---------- row-scan epilogue: 4 dump phases of 32 cols ----------
    float bv[TOPK]; int bj[TOPK];
    #pragma unroll
    for (int s = 0; s < TOPK; s++) { bv[s] = -1e30f; bj[s] = 0x7fffffff; }

    const int erow = t & 127, scb = (t >> 7) * 16;
    #pragma unroll
    for (int p = 0; p < 4; p++) {
        __syncthreads();
        if (wc == (p >> 1)) {
            const int ni0 = (p & 1) * 2;
            #pragma unroll
            for (int mi = 0; mi < 4; mi++)
                #pragma unroll
                for (int n2 = 0; n2 < 2; n2++) {
                    int colb = n2 * 16 + l15;
                    int rowb = wr * 64 + mi * 16 + quad * 4;
                    f32x4 v = acc[mi][ni0 + n2];
                    #pragma unroll
                    for (int r = 0; r < 4; r++) sS[(rowb + r) * 33 + colb] = v[r];
                }
        }
        __syncthreads();
        int jbase = ci * 128 + p * 32 + scb;
        for (int c = 0; c < 16; c++) {
            float v = sS[erow * 33 + scb + c];
            if (v > bv[TOPK - 1]) topk_insert(v, jbase + c, bv, bj);
        }
    }
    __syncthreads();
    if (t >= 128) {
        #pragma unroll
        for (int s = 0; s < TOPK; s++) { mv[(t - 128) * TOPK + s] = bv[s]; mj[(t - 128) * TOPK + s] = bj[s]; }
    }
    __syncthreads();
    if (t < 128) {
        #pragma unroll
        for (int s0 = 0; s0 < TOPK; s0++) {
            float v = mv[t * TOPK + s0];
            if (v > bv[TOPK - 1]) topk_insert(v, mj[t * TOPK + s0], bv, bj);
        }
        size_t o = ((size_t)(ri * 128 + t) * NT + ci) * TOPK;
        #pragma unroll
        for (int s = 0; s < TOPK; s++) { candv[o + s] = bv[s]; candi[o + s] = bj[s]; }
    }

    // ---------- column-scan epilogue (triangular tiles only) ----------
    // By symmetry, column co of this tile = row ci*128+co vs columns ri*128+a.
    // Transposed dump in 4 phases over original-row chunks of 32; scanners walk
    // a ascending (j ascending) -> same tie semantics as row-scan.
    if (tri) {
        #pragma unroll
        for (int s = 0; s < TOPK; s++) { bv[s] = -1e30f; bj[s] = 0x7fffffff; }
        #pragma unroll
        for (int p = 0; p < 4; p++) {
            __syncthreads();
            if (wr == (p >> 1)) {
                const int mi0 = (p & 1) * 2;
                #pragma unroll
                for (int m2 = 0; m2 < 2; m2++)
                    #pragma unroll
                    for (int ni = 0; ni < 4; ni++) {
                        int co = wc * 64 + ni * 16 + l15;          // original col
                        int lr = m2 * 16 + quad * 4;               // row within chunk
                        f32x4 v = acc[mi0 + m2][ni];
                        #pragma unroll
                        for (int r = 0; r < 4; r++) sS[co * 33 + lr + r] = v[r];
                    }
            }
            __syncthreads();
            int jbase = ri * 128 + p * 32 + scb;
            for (int c = 0; c < 16; c++) {
                float v = sS[erow * 33 + scb + c];
                if (v > bv[TOPK - 1]) topk_insert(v, jbase + c, bv, bj);
            }
        }
        __syncthreads();
        if (t >= 128) {
            #pragma unroll
            for (int s = 0; s < TOPK; s++) { mv[(t - 128) * TOPK + s] = bv[s]; mj[(t - 128) * TOPK + s] = bj[s]; }
        }
        __syncthreads();
        if (t < 128) {
            #pragma unroll
            for (int s0 = 0; s0 < TOPK; s0++) {
                float v = mv[t * TOPK + s0];
                if (v > bv[TOPK - 1]) topk_insert(v, mj[t * TOPK + s0], bv, bj);
            }
            size_t o = ((size_t)(ci * 128 + t) * NT + ri) * TOPK;
            #pragma unroll
            for (int s = 0; s < TOPK; s++) { candv[o + s] = bv[s]; candi[o + s] = bj[s]; }
        }
    }
}

// ------- fused merge (wave-parallel) + sparse loss + global atomic accumulate ----
// 256-thread blocks, 4 rows/block (wave per row). Per wave: 6-round xor merge of
// the 64 per-tile sorted top-6 lists (low-lane base preserves earlier-j ties),
// then deferred-reduction loss with ONE wave reduction. Clamp dropped (d2 =
// sqi+sqj-2dot, dot <= ~0.25 for distinct normalized rows -> max(.,0) dead).
__global__ __launch_bounds__(256) void k_mergeloss(const float* __restrict__ candv,
                                                   const int* __restrict__ candi,
                                                   const float* __restrict__ hcn,
                                                   const float* __restrict__ sq,
                                                   const int* __restrict__ labp,
                                                   float* __restrict__ out) {
    __shared__ float bsum[4];
    const int w = threadIdx.x >> 6, lane = threadIdx.x & 63;
    const int i = blockIdx.x * 4 + w;

    const float* cv = candv + ((size_t)i * NT + lane) * TOPK;
    const int*   cj = candi + ((size_t)i * NT + lane) * TOPK;
    float bv[TOPK]; int bj[TOPK];
    #pragma unroll
    for (int s = 0; s < TOPK; s++) { bv[s] = cv[s]; bj[s] = cj[s]; }

    #pragma unroll
    for (int off = 1; off < 64; off <<= 1) {
        float pv[TOPK]; int pj[TOPK];
        #pragma unroll
        for (int s = 0; s < TOPK; s++) {
            pv[s] = __shfl_xor(bv[s], off, 64);
            pj[s] = __shfl_xor(bj[s], off, 64);
        }
        bool ilow = (lane & off) == 0;
        float av[TOPK], iv[TOPK]; int aj[TOPK], ij[TOPK];
        #pragma unroll
        for (int s = 0; s < TOPK; s++) {
            av[s] = ilow ? bv[s] : pv[s];  aj[s] = ilow ? bj[s] : pj[s];
            iv[s] = ilow ? pv[s] : bv[s];  ij[s] = ilow ? pj[s] : bj[s];
        }
        #pragma unroll
        for (int s = 0; s < TOPK; s++)
            if (iv[s] > av[TOPK - 1]) topk_insert(iv[s], ij[s], av, aj);
        #pragma unroll
        for (int s = 0; s < TOPK; s++) { bv[s] = av[s]; bj[s] = aj[s]; }
    }

    // loss: ranks 1..5 (rank 0 is self). Deferred reduction.
    const float* hi = hcn + (size_t)i * D;
    float4 h0 = *(const float4*)(hi + lane * 4);
    float4 h1 = *(const float4*)(hi + lane * 4 + 256);
    float4 h2 = *(const float4*)(hi + lane * 4 + 512);
    float sqi = sq[i];
    int li = labp[i];
    float part = 0.f;
    float base = 0.f;
    #pragma unroll
    for (int s = 1; s <= KNB; s++) {
        int j = bj[s];
        if (j >= BC) continue;
        const float* hj = hcn + (size_t)j * D;
        float4 g0 = *(const float4*)(hj + lane * 4);
        float4 g1 = *(const float4*)(hj + lane * 4 + 256);
        float4 g2 = *(const float4*)(hj + lane * 4 + 512);
        float d = h0.x * g0.x + h0.y * g0.y + h0.z * g0.z + h0.w * g0.w
                + h1.x * g1.x + h1.y * g1.y + h1.z * g1.z + h1.w * g1.w
                + h2.x * g2.x + h2.y * g2.y + h2.z * g2.z + h2.w * g2.w;
        float e = (li == labp[j]) ? 1.0f : -1.0f;
        part += e * (-2.0f) * d;
        if (lane == 0) base += e * (sqi + sq[j]);
    }
    part += base;
    #pragma unroll
    for (int off = 32; off; off >>= 1) part += __shfl_xor(part, off, 64);
    if (lane == 0) bsum[w] = part;
    __syncthreads();
    if (threadIdx.x == 0) {
        float s = bsum[0] + bsum[1] + bsum[2] + bsum[3];
        unsafeAtomicAdd(out, 0.5f * s / ((float)BC * (float)BC));
    }
}

extern "C" void kernel_launch(void* const* d_in, const int* in_sizes, int n_in,
                              void* d_out, int out_size, void* d_ws, size_t ws_size,
                              hipStream_t stream) {
    const float* hc   = (const float*)d_in[0];  // hidden_current  (4096,768)
    const float* hp   = (const float*)d_in[1];  // hidden_previous (8192,768)
    const int*   labp = (const int*)d_in[3];    // labels_previous (8192,)
    float* out = (float*)d_out;

    // workspace layout (~38 MB)
    unsigned short* hpnb = (unsigned short*)d_ws;          // BP*D bf16 (pre-swizzled)
    float* hcn  = (float*)(hpnb + (size_t)BP * D);         // BC*D f32
    float* sq   = hcn + (size_t)BC * D;                    // BC
    float* candv = sq + BC;                                // BC*NT*TOPK
    int*   candi = (int*)(candv + (size_t)BC * NT * TOPK); // BC*NT*TOPK

    k_norm<<<dim3(BP + BC), dim3(256), 0, stream>>>(hp, hc, hpnb, hcn, sq, out);
    k_simtop<<<dim3(NBLK), dim3(256), 0, stream>>>(hpnb, candv, candi);
    k_mergeloss<<<dim3(BC / 4), dim3(256), 0, stream>>>(candv, candi, hcn, sq, labp, out);
}

// Round 14
// 182.519 us; speedup vs baseline: 1.1107x; 1.0415x over previous
//
#include <hip/hip_runtime.h>

#define BC 4096      // rows of hidden_current
#define BP 8192      // rows of hidden_previous
#define D  768
#define KNB 5
#define TOPK 6
#define NT (BP / 128)   // 64 column tiles of the similarity matrix

typedef __bf16 bf16x8 __attribute__((ext_vector_type(8)));
typedef float  f32x4  __attribute__((ext_vector_type(4)));

__device__ __forceinline__ unsigned short f2bf(float f) {
    unsigned int u = __float_as_uint(f);
    u += 0x7fffu + ((u >> 16) & 1u);          // round-to-nearest-even
    return (unsigned short)(u >> 16);
}

__device__ __forceinline__ void gload16(const void* g, void* l) {
    __builtin_amdgcn_global_load_lds(
        (const __attribute__((address_space(1))) unsigned int*)g,
        (__attribute__((address_space(3))) unsigned int*)l, 16, 0, 0);
}

// Branchless insertion network, STATIC indices only (r6 lesson: runtime-indexed
// private arrays -> scratch). Strict >: ties keep the incumbent (earlier j),
// matching reference sequential j-ascending top_k.
__device__ __forceinline__ void topk_insert(float v, int j, float* bv, int* bj) {
    #pragma unroll
    for (int q = TOPK - 1; q >= 1; q--) {
        bool up   = v > bv[q - 1];
        bool here = (v > bv[q]) && !up;
        bv[q] = up ? bv[q - 1] : (here ? v : bv[q]);
        bj[q] = up ? bj[q - 1] : (here ? j : bj[q]);
    }
    if (v > bv[0]) { bv[0] = v; bj[0] = j; }
}

// ---------------- fused normalize: hp -> bf16 ranking copy, hc -> fp32 + sq ------
// hpnb is written PRE-SWIZZLED: element e of row r is stored at e ^ ((r&7)<<3)
// (16B chunks XOR-rotated within each 128B group). The monotone global_load_lds
// staging in k_simtop then lands the XOR-swizzled LDS layout for free, making
// fragment ds_read_b128 conflict-free (r10 win: conflicts 2.0e7 -> 1.1e6).
// Writes stay within the same 128B lines, so coalescing is unchanged.
__global__ __launch_bounds__(256) void k_norm(const float* __restrict__ hp,
                                              const float* __restrict__ hc,
                                              unsigned short* __restrict__ hpnb,
                                              float* __restrict__ hcn,
                                              float* __restrict__ sqout,
                                              float* __restrict__ out) {
    int b = blockIdx.x;
    int t = threadIdx.x;
    if (b == 0 && t == 0) out[0] = 0.0f;
    bool isP = (b < BP);
    int row = isP ? b : (b - BP);
    const float* xr = (isP ? hp : hc) + (size_t)row * D;
    float v0 = xr[t], v1 = xr[t + 256], v2 = xr[t + 512];
    float s = v0 * v0 + v1 * v1 + v2 * v2;
    #pragma unroll
    for (int off = 32; off; off >>= 1) s += __shfl_xor(s, off, 64);
    __shared__ float wsum[4];
    if ((t & 63) == 0) wsum[t >> 6] = s;
    __syncthreads();
    float tot = wsum[0] + wsum[1] + wsum[2] + wsum[3];
    float rinv = 1.0f / fmaxf(sqrtf(tot), 1e-12f);
    if (isP) {
        unsigned short* yr = hpnb + (size_t)row * D;
        int rx = (row & 7) << 3;                       // chunk swizzle (bits 3..5)
        yr[t ^ rx]         = f2bf(v0 * rinv);
        yr[(t + 256) ^ rx] = f2bf(v1 * rinv);
        yr[(t + 512) ^ rx] = f2bf(v2 * rinv);
    } else {
        float* yr = hcn + (size_t)row * D;
        yr[t] = v0 * rinv; yr[t + 256] = v1 * rinv; yr[t + 512] = v2 * rinv;
        if (t == 0) sqout[row] = tot * rinv * rinv;
    }
}

// ---------------- bf16 MFMA similarity tile + fused per-row top-6 ----------------
// grid (32, 64): 128x128 tile of S = hp_bf16[0:4096] . hp_bf16^T
// Staging: global_load_lds width=16, MONOTONE lane->address map (m97 pattern,
// zero staging VALU). Source hpnb is pre-swizzled (see k_norm), so LDS holds
// the XOR layout and fragment reads at (quad^(l15&7))*16 are conflict-free.
// This is the measured optimum of this structure (r10: 82.5 us, 624 TF):
// r11 (256,4) spilled; r12/r13 symmetry regressed (tail raggedness + spill);
// r7 VGPR-round-trip staging and r8 unswizzled LDS were neutral-or-worse.
__global__ __launch_bounds__(256, 3) void k_simtop(const unsigned short* __restrict__ hp,
                                                   float* __restrict__ candv,
                                                   int* __restrict__ candi) {
    __shared__ char smem[39424];
    unsigned short* sA = (unsigned short*)smem;          // [128 rows][64 k] swizzled
    unsigned short* sB = sA + 128 * 64;
    float* sS = (float*)smem;                            // [128][65] score buffer (alias)
    float* mv = (float*)(smem + 33280);                  // [128][6] partner top-6 vals
    int*   mj = (int*)(smem + 33280 + 3072);             // [128][6] partner top-6 idx

    const int t = threadIdx.x;
    const int l = t & 63;
    const int w = t >> 6;
    const int l15 = l & 15, quad = l >> 4;
    const int wr = w >> 1, wc = w & 1;
    const int ri = blockIdx.x, ci = blockIdx.y;

    // per-lane global source: row group w*32 + p*8 + (l>>3), chunk l&7 (monotone)
    const int srow = l >> 3, sch = l & 7;
    const unsigned short* Ag = hp + (size_t)(ri * 128 + w * 32 + srow) * D + sch * 8;
    const unsigned short* Bg = hp + (size_t)(ci * 128 + w * 32 + srow) * D + sch * 8;
    unsigned short* la = sA + (w * 32) * 64;             // wave-uniform LDS bases
    unsigned short* lb = sB + (w * 32) * 64;

    f32x4 acc[4][4];
    #pragma unroll
    for (int i = 0; i < 4; i++)
        #pragma unroll
        for (int j = 0; j < 4; j++) acc[i][j] = (f32x4){0.f, 0.f, 0.f, 0.f};

    // fragment LDS chunk offsets (lane-constant, conflict-free): original
    // k-chunk q of row r sits at LDS pos q^(r&7); frag rows have r&7 == l15&7.
    const int x7  = l15 & 7;
    const int ch0 = (quad ^ x7) * 16;
    const int ch1 = ((quad + 4) ^ x7) * 16;

    for (int kk = 0; kk < D; kk += 64) {
        __syncthreads();                                 // prev iter's LDS reads done
        #pragma unroll
        for (int p = 0; p < 4; p++) {
            gload16(Ag + (size_t)(p * 8) * D + kk, la + (p * 8) * 64);
            gload16(Bg + (size_t)(p * 8) * D + kk, lb + (p * 8) * 64);
        }
        __syncthreads();                                 // vmcnt drain + tile ready
        #pragma unroll
        for (int ks = 0; ks < 2; ks++) {
            const int ch = ks ? ch1 : ch0;
            bf16x8 af[4], bfr[4];
            #pragma unroll
            for (int mi = 0; mi < 4; mi++)
                af[mi] = *(const bf16x8*)((const char*)sA + (wr * 64 + mi * 16 + l15) * 128 + ch);
            #pragma unroll
            for (int ni = 0; ni < 4; ni++)
                bfr[ni] = *(const bf16x8*)((const char*)sB + (wc * 64 + ni * 16 + l15) * 128 + ch);
            #pragma unroll
            for (int mi = 0; mi < 4; mi++)
                #pragma unroll
                for (int ni = 0; ni < 4; ni++)
                    acc[mi][ni] = __builtin_amdgcn_mfma_f32_16x16x32_bf16(af[mi], bfr[ni], acc[mi][ni], 0, 0, 0);
        }
    }

    // epilogue: 2 dump phases of 64 cols; 256 threads scan 2-per-row (32 cols each)
    float bv[TOPK]; int bj[TOPK];
    #pragma unroll
    for (int s = 0; s < TOPK; s++) { bv[s] = -1e30f; bj[s] = 0x7fffffff; }

    const int erow = t & 127, scb = (t >> 7) * 32;
    #pragma unroll
    for (int h = 0; h < 2; h++) {
        __syncthreads();
        if (wc == h) {
            #pragma unroll
            for (int mi = 0; mi < 4; mi++)
                #pragma unroll
                for (int ni = 0; ni < 4; ni++) {
                    int colb = ni * 16 + l15;
                    int rowb = wr * 64 + mi * 16 + quad * 4;
                    f32x4 v = acc[mi][ni];
                    #pragma unroll
                    for (int r = 0; r < 4; r++) sS[(rowb + r) * 65 + colb] = v[r];
                }
        }
        __syncthreads();
        int jbase = ci * 128 + h * 64 + scb;
        for (int c = 0; c < 32; c++) {
            float v = sS[erow * 65 + scb + c];
            if (v > bv[TOPK - 1]) topk_insert(v, jbase + c, bv, bj);
        }
    }

    // merge the two half-row scanners
    __syncthreads();
    if (t >= 128) {
        #pragma unroll
        for (int s = 0; s < TOPK; s++) { mv[(t - 128) * TOPK + s] = bv[s]; mj[(t - 128) * TOPK + s] = bj[s]; }
    }
    __syncthreads();
    if (t < 128) {
        #pragma unroll
        for (int s0 = 0; s0 < TOPK; s0++) {
            float v = mv[t * TOPK + s0];
            if (v > bv[TOPK - 1]) topk_insert(v, mj[t * TOPK + s0], bv, bj);
        }
        size_t o = ((size_t)(ri * 128 + t) * NT + ci) * TOPK;
        #pragma unroll
        for (int s = 0; s < TOPK; s++) { candv[o + s] = bv[s]; candi[o + s] = bj[s]; }
    }
}

// ------- fused merge (wave-parallel) + sparse loss + global atomic accumulate ----
// 256-thread blocks, 4 rows/block (wave per row). Per wave: 6-round xor merge of
// the 64 per-tile sorted top-6 lists (low-lane base preserves earlier-j ties),
// then deferred-reduction loss: per-lane dot partials across all 5 neighbors,
// ONE wave reduction at the end. Clamp dropped: d2 = sqi+sqj-2dot with
// dot <= ~0.25 for distinct normalized vectors, so max(.,0) is dead.
__global__ __launch_bounds__(256) void k_mergeloss(const float* __restrict__ candv,
                                                   const int* __restrict__ candi,
                                                   const float* __restrict__ hcn,
                                                   const float* __restrict__ sq,
                                                   const int* __restrict__ labp,
                                                   float* __restrict__ out) {
    __shared__ float bsum[4];
    const int w = threadIdx.x >> 6, lane = threadIdx.x & 63;
    const int i = blockIdx.x * 4 + w;

    const float* cv = candv + ((size_t)i * NT + lane) * TOPK;
    const int*   cj = candi + ((size_t)i * NT + lane) * TOPK;
    float bv[TOPK]; int bj[TOPK];
    #pragma unroll
    for (int s = 0; s < TOPK; s++) { bv[s] = cv[s]; bj[s] = cj[s]; }

    #pragma unroll
    for (int off = 1; off < 64; off <<= 1) {
        float pv[TOPK]; int pj[TOPK];
        #pragma unroll
        for (int s = 0; s < TOPK; s++) {
            pv[s] = __shfl_xor(bv[s], off, 64);
            pj[s] = __shfl_xor(bj[s], off, 64);
        }
        bool ilow = (lane & off) == 0;
        float av[TOPK], iv[TOPK]; int aj[TOPK], ij[TOPK];
        #pragma unroll
        for (int s = 0; s < TOPK; s++) {
            av[s] = ilow ? bv[s] : pv[s];  aj[s] = ilow ? bj[s] : pj[s];
            iv[s] = ilow ? pv[s] : bv[s];  ij[s] = ilow ? pj[s] : bj[s];
        }
        #pragma unroll
        for (int s = 0; s < TOPK; s++)
            if (iv[s] > av[TOPK - 1]) topk_insert(iv[s], ij[s], av, aj);
        #pragma unroll
        for (int s = 0; s < TOPK; s++) { bv[s] = av[s]; bj[s] = aj[s]; }
    }

    // loss: ranks 1..5 (rank 0 is self). Deferred reduction.
    const float* hi = hcn + (size_t)i * D;
    float4 h0 = *(const float4*)(hi + lane * 4);
    float4 h1 = *(const float4*)(hi + lane * 4 + 256);
    float4 h2 = *(const float4*)(hi + lane * 4 + 512);
    float sqi = sq[i];
    int li = labp[i];
    float part = 0.f;          // per-lane: sum_s e_s * (-2) * dot_partial
    float base = 0.f;          // lane-0 only: sum_s e_s * (sqi + sqj)
    #pragma unroll
    for (int s = 1; s <= KNB; s++) {
        int j = bj[s];
        if (j >= BC) continue;
        const float* hj = hcn + (size_t)j * D;
        float4 g0 = *(const float4*)(hj + lane * 4);
        float4 g1 = *(const float4*)(hj + lane * 4 + 256);
        float4 g2 = *(const float4*)(hj + lane * 4 + 512);
        float d = h0.x * g0.x + h0.y * g0.y + h0.z * g0.z + h0.w * g0.w
                + h1.x * g1.x + h1.y * g1.y + h1.z * g1.z + h1.w * g1.w
                + h2.x * g2.x + h2.y * g2.y + h2.z * g2.z + h2.w * g2.w;
        float e = (li == labp[j]) ? 1.0f : -1.0f;
        part += e * (-2.0f) * d;
        if (lane == 0) base += e * (sqi + sq[j]);
    }
    part += base;              // only lane 0 carries base
    #pragma unroll
    for (int off = 32; off; off >>= 1) part += __shfl_xor(part, off, 64);
    if (lane == 0) bsum[w] = part;
    __syncthreads();
    if (threadIdx.x == 0) {
        float s = bsum[0] + bsum[1] + bsum[2] + bsum[3];
        unsafeAtomicAdd(out, 0.5f * s / ((float)BC * (float)BC));
    }
}

extern "C" void kernel_launch(void* const* d_in, const int* in_sizes, int n_in,
                              void* d_out, int out_size, void* d_ws, size_t ws_size,
                              hipStream_t stream) {
    const float* hc   = (const float*)d_in[0];  // hidden_current  (4096,768)
    const float* hp   = (const float*)d_in[1];  // hidden_previous (8192,768)
    const int*   labp = (const int*)d_in[3];    // labels_previous (8192,)
    float* out = (float*)d_out;

    // workspace layout (~38 MB)
    unsigned short* hpnb = (unsigned short*)d_ws;          // BP*D bf16 (pre-swizzled)
    float* hcn  = (float*)(hpnb + (size_t)BP * D);         // BC*D f32
    float* sq   = hcn + (size_t)BC * D;                    // BC
    float* candv = sq + BC;                                // BC*NT*TOPK
    int*   candi = (int*)(candv + (size_t)BC * NT * TOPK); // BC*NT*TOPK

    k_norm<<<dim3(BP + BC), dim3(256), 0, stream>>>(hp, hc, hpnb, hcn, sq, out);
    k_simtop<<<dim3(BC / 128, NT), dim3(256), 0, stream>>>(hpnb, candv, candi);
    k_mergeloss<<<dim3(BC / 4), dim3(256), 0, stream>>>(candv, candi, hcn, sq, labp, out);
}

// Round 15
// 176.112 us; speedup vs baseline: 1.1511x; 1.0364x over previous
//
#include <hip/hip_runtime.h>

#define BC 4096      // rows of hidden_current
#define BP 8192      // rows of hidden_previous
#define D  768
#define KNB 5
#define TOPK 6
#define NT (BP / 128)   // 64 column tiles of the similarity matrix

typedef __bf16 bf16x8 __attribute__((ext_vector_type(8)));
typedef float  f32x4  __attribute__((ext_vector_type(4)));

__device__ __forceinline__ unsigned short f2bf(float f) {
    unsigned int u = __float_as_uint(f);
    u += 0x7fffu + ((u >> 16) & 1u);          // round-to-nearest-even
    return (unsigned short)(u >> 16);
}

__device__ __forceinline__ void gload16(const void* g, void* l) {
    __builtin_amdgcn_global_load_lds(
        (const __attribute__((address_space(1))) unsigned int*)g,
        (__attribute__((address_space(3))) unsigned int*)l, 16, 0, 0);
}

// Branchless insertion network, STATIC indices only (r6 lesson: runtime-indexed
// private arrays -> scratch). Strict >: ties keep the incumbent (earlier j),
// matching reference sequential j-ascending top_k.
__device__ __forceinline__ void topk_insert(float v, int j, float* bv, int* bj) {
    #pragma unroll
    for (int q = TOPK - 1; q >= 1; q--) {
        bool up   = v > bv[q - 1];
        bool here = (v > bv[q]) && !up;
        bv[q] = up ? bv[q - 1] : (here ? v : bv[q]);
        bj[q] = up ? bj[q - 1] : (here ? j : bj[q]);
    }
    if (v > bv[0]) { bv[0] = v; bj[0] = j; }
}

// ---------------- fused normalize: hp -> bf16 ranking copy, hc -> fp32 + sq ------
// hpnb is written PRE-SWIZZLED: element e of row r is stored at e ^ ((r&7)<<3)
// (16B chunks XOR-rotated within each 128B group). The monotone global_load_lds
// staging in k_simtop then lands the XOR-swizzled LDS layout for free, making
// fragment ds_read_b128 conflict-free (r10 win: conflicts 2.0e7 -> 1.1e6).
// Writes stay within the same 128B lines, so coalescing is unchanged.
__global__ __launch_bounds__(256) void k_norm(const float* __restrict__ hp,
                                              const float* __restrict__ hc,
                                              unsigned short* __restrict__ hpnb,
                                              float* __restrict__ hcn,
                                              float* __restrict__ sqout,
                                              float* __restrict__ out) {
    int b = blockIdx.x;
    int t = threadIdx.x;
    if (b == 0 && t == 0) out[0] = 0.0f;
    bool isP = (b < BP);
    int row = isP ? b : (b - BP);
    const float* xr = (isP ? hp : hc) + (size_t)row * D;
    float v0 = xr[t], v1 = xr[t + 256], v2 = xr[t + 512];
    float s = v0 * v0 + v1 * v1 + v2 * v2;
    #pragma unroll
    for (int off = 32; off; off >>= 1) s += __shfl_xor(s, off, 64);
    __shared__ float wsum[4];
    if ((t & 63) == 0) wsum[t >> 6] = s;
    __syncthreads();
    float tot = wsum[0] + wsum[1] + wsum[2] + wsum[3];
    float rinv = 1.0f / fmaxf(sqrtf(tot), 1e-12f);
    if (isP) {
        unsigned short* yr = hpnb + (size_t)row * D;
        int rx = (row & 7) << 3;                       // chunk swizzle (bits 3..5)
        yr[t ^ rx]         = f2bf(v0 * rinv);
        yr[(t + 256) ^ rx] = f2bf(v1 * rinv);
        yr[(t + 512) ^ rx] = f2bf(v2 * rinv);
    } else {
        float* yr = hcn + (size_t)row * D;
        yr[t] = v0 * rinv; yr[t + 256] = v1 * rinv; yr[t + 512] = v2 * rinv;
        if (t == 0) sqout[row] = tot * rinv * rinv;
    }
}

// ---------------- bf16 MFMA similarity tile + fused per-row top-6 ----------------
// 2048 blocks: 128x128 tiles of S = hp_bf16[0:4096] . hp_bf16^T
// Staging: global_load_lds width=16, MONOTONE lane->address map (m97 pattern);
// source hpnb pre-swizzled (k_norm) -> conflict-free fragment reads.
// NEW (r15): XCD-locality super-tile swizzle. Tile grid 32x64 grouped into
// 8x8 super-tiles (8 A-panels + 8 B-panels = 3.1 MB < 4 MB per-XCD L2).
// Block b -> XCD b&7 (round-robin dispatch heuristic); each XCD's consecutive
// blocks walk ONE super-tile, so its reads hit its private L2 instead of L3
// (805 MB of tile re-reads vs 25 MB array; FETCH shows 94% cached — the L2/L3
// split is what this targets).
__global__ __launch_bounds__(256, 3) void k_simtop(const unsigned short* __restrict__ hp,
                                                   float* __restrict__ candv,
                                                   int* __restrict__ candi) {
    __shared__ char smem[39424];
    unsigned short* sA = (unsigned short*)smem;          // [128 rows][64 k] swizzled
    unsigned short* sB = sA + 128 * 64;
    float* sS = (float*)smem;                            // [128][65] score buffer (alias)
    float* mv = (float*)(smem + 33280);                  // [128][6] partner top-6 vals
    int*   mj = (int*)(smem + 33280 + 3072);             // [128][6] partner top-6 idx

    const int t = threadIdx.x;
    const int l = t & 63;
    const int w = t >> 6;
    const int l15 = l & 15, quad = l >> 4;
    const int wr = w >> 1, wc = w & 1;

    // super-tile swizzle: xcd = b&7, slot = b>>3; super = (slot>>6)*8 + xcd
    // (4x8 super grid over 32x64 tiles); within-super 8x8 walk.
    int ri, ci;
    {
        int b = blockIdx.x;
        int super_id = (((b >> 9) & 3) << 3) | (b & 7);  // 0..31
        int within = (b >> 3) & 63;                       // 0..63
        ri = (super_id >> 3) * 8 + (within >> 3);         // 0..31
        ci = (super_id & 7) * 8 + (within & 7);           // 0..63
    }

    // per-lane global source: row group w*32 + p*8 + (l>>3), chunk l&7 (monotone)
    const int srow = l >> 3, sch = l & 7;
    const unsigned short* Ag = hp + (size_t)(ri * 128 + w * 32 + srow) * D + sch * 8;
    const unsigned short* Bg = hp + (size_t)(ci * 128 + w * 32 + srow) * D + sch * 8;
    unsigned short* la = sA + (w * 32) * 64;             // wave-uniform LDS bases
    unsigned short* lb = sB + (w * 32) * 64;

    f32x4 acc[4][4];
    #pragma unroll
    for (int i = 0; i < 4; i++)
        #pragma unroll
        for (int j = 0; j < 4; j++) acc[i][j] = (f32x4){0.f, 0.f, 0.f, 0.f};

    // fragment LDS chunk offsets (lane-constant, conflict-free): original
    // k-chunk q of row r sits at LDS pos q^(r&7); frag rows have r&7 == l15&7.
    const int x7  = l15 & 7;
    const int ch0 = (quad ^ x7) * 16;
    const int ch1 = ((quad + 4) ^ x7) * 16;

    for (int kk = 0; kk < D; kk += 64) {
        __syncthreads();                                 // prev iter's LDS reads done
        #pragma unroll
        for (int p = 0; p < 4; p++) {
            gload16(Ag + (size_t)(p * 8) * D + kk, la + (p * 8) * 64);
            gload16(Bg + (size_t)(p * 8) * D + kk, lb + (p * 8) * 64);
        }
        __syncthreads();                                 // vmcnt drain + tile ready
        #pragma unroll
        for (int ks = 0; ks < 2; ks++) {
            const int ch = ks ? ch1 : ch0;
            bf16x8 af[4], bfr[4];
            #pragma unroll
            for (int mi = 0; mi < 4; mi++)
                af[mi] = *(const bf16x8*)((const char*)sA + (wr * 64 + mi * 16 + l15) * 128 + ch);
            #pragma unroll
            for (int ni = 0; ni < 4; ni++)
                bfr[ni] = *(const bf16x8*)((const char*)sB + (wc * 64 + ni * 16 + l15) * 128 + ch);
            #pragma unroll
            for (int mi = 0; mi < 4; mi++)
                #pragma unroll
                for (int ni = 0; ni < 4; ni++)
                    acc[mi][ni] = __builtin_amdgcn_mfma_f32_16x16x32_bf16(af[mi], bfr[ni], acc[mi][ni], 0, 0, 0);
        }
    }

    // epilogue: 2 dump phases of 64 cols; 256 threads scan 2-per-row (32 cols each)
    float bv[TOPK]; int bj[TOPK];
    #pragma unroll
    for (int s = 0; s < TOPK; s++) { bv[s] = -1e30f; bj[s] = 0x7fffffff; }

    const int erow = t & 127, scb = (t >> 7) * 32;
    #pragma unroll
    for (int h = 0; h < 2; h++) {
        __syncthreads();
        if (wc == h) {
            #pragma unroll
            for (int mi = 0; mi < 4; mi++)
                #pragma unroll
                for (int ni = 0; ni < 4; ni++) {
                    int colb = ni * 16 + l15;
                    int rowb = wr * 64 + mi * 16 + quad * 4;
                    f32x4 v = acc[mi][ni];
                    #pragma unroll
                    for (int r = 0; r < 4; r++) sS[(rowb + r) * 65 + colb] = v[r];
                }
        }
        __syncthreads();
        int jbase = ci * 128 + h * 64 + scb;
        for (int c = 0; c < 32; c++) {
            float v = sS[erow * 65 + scb + c];
            if (v > bv[TOPK - 1]) topk_insert(v, jbase + c, bv, bj);
        }
    }

    // merge the two half-row scanners
    __syncthreads();
    if (t >= 128) {
        #pragma unroll
        for (int s = 0; s < TOPK; s++) { mv[(t - 128) * TOPK + s] = bv[s]; mj[(t - 128) * TOPK + s] = bj[s]; }
    }
    __syncthreads();
    if (t < 128) {
        #pragma unroll
        for (int s0 = 0; s0 < TOPK; s0++) {
            float v = mv[t * TOPK + s0];
            if (v > bv[TOPK - 1]) topk_insert(v, mj[t * TOPK + s0], bv, bj);
        }
        size_t o = ((size_t)(ri * 128 + t) * NT + ci) * TOPK;
        #pragma unroll
        for (int s = 0; s < TOPK; s++) { candv[o + s] = bv[s]; candi[o + s] = bj[s]; }
    }
}

// ------- fused merge (wave-parallel) + sparse loss + global atomic accumulate ----
// 256-thread blocks, 4 rows/block (wave per row). Per wave: 6-round xor merge of
// the 64 per-tile sorted top-6 lists (low-lane base preserves earlier-j ties),
// then deferred-reduction loss: per-lane dot partials across all 5 neighbors,
// ONE wave reduction at the end. Clamp dropped: d2 = sqi+sqj-2dot with
// dot <= ~0.25 for distinct normalized vectors, so max(.,0) is dead.
__global__ __launch_bounds__(256) void k_mergeloss(const float* __restrict__ candv,
                                                   const int* __restrict__ candi,
                                                   const float* __restrict__ hcn,
                                                   const float* __restrict__ sq,
                                                   const int* __restrict__ labp,
                                                   float* __restrict__ out) {
    __shared__ float bsum[4];
    const int w = threadIdx.x >> 6, lane = threadIdx.x & 63;
    const int i = blockIdx.x * 4 + w;

    const float* cv = candv + ((size_t)i * NT + lane) * TOPK;
    const int*   cj = candi + ((size_t)i * NT + lane) * TOPK;
    float bv[TOPK]; int bj[TOPK];
    #pragma unroll
    for (int s = 0; s < TOPK; s++) { bv[s] = cv[s]; bj[s] = cj[s]; }

    #pragma unroll
    for (int off = 1; off < 64; off <<= 1) {
        float pv[TOPK]; int pj[TOPK];
        #pragma unroll
        for (int s = 0; s < TOPK; s++) {
            pv[s] = __shfl_xor(bv[s], off, 64);
            pj[s] = __shfl_xor(bj[s], off, 64);
        }
        bool ilow = (lane & off) == 0;
        float av[TOPK], iv[TOPK]; int aj[TOPK], ij[TOPK];
        #pragma unroll
        for (int s = 0; s < TOPK; s++) {
            av[s] = ilow ? bv[s] : pv[s];  aj[s] = ilow ? bj[s] : pj[s];
            iv[s] = ilow ? pv[s] : bv[s];  ij[s] = ilow ? pj[s] : bj[s];
        }
        #pragma unroll
        for (int s = 0; s < TOPK; s++)
            if (iv[s] > av[TOPK - 1]) topk_insert(iv[s], ij[s], av, aj);
        #pragma unroll
        for (int s = 0; s < TOPK; s++) { bv[s] = av[s]; bj[s] = aj[s]; }
    }

    // loss: ranks 1..5 (rank 0 is self). Deferred reduction.
    const float* hi = hcn + (size_t)i * D;
    float4 h0 = *(const float4*)(hi + lane * 4);
    float4 h1 = *(const float4*)(hi + lane * 4 + 256);
    float4 h2 = *(const float4*)(hi + lane * 4 + 512);
    float sqi = sq[i];
    int li = labp[i];
    float part = 0.f;          // per-lane: sum_s e_s * (-2) * dot_partial
    float base = 0.f;          // lane-0 only: sum_s e_s * (sqi + sqj)
    #pragma unroll
    for (int s = 1; s <= KNB; s++) {
        int j = bj[s];
        if (j >= BC) continue;
        const float* hj = hcn + (size_t)j * D;
        float4 g0 = *(const float4*)(hj + lane * 4);
        float4 g1 = *(const float4*)(hj + lane * 4 + 256);
        float4 g2 = *(const float4*)(hj + lane * 4 + 512);
        float d = h0.x * g0.x + h0.y * g0.y + h0.z * g0.z + h0.w * g0.w
                + h1.x * g1.x + h1.y * g1.y + h1.z * g1.z + h1.w * g1.w
                + h2.x * g2.x + h2.y * g2.y + h2.z * g2.z + h2.w * g2.w;
        float e = (li == labp[j]) ? 1.0f : -1.0f;
        part += e * (-2.0f) * d;
        if (lane == 0) base += e * (sqi + sq[j]);
    }
    part += base;              // only lane 0 carries base
    #pragma unroll
    for (int off = 32; off; off >>= 1) part += __shfl_xor(part, off, 64);
    if (lane == 0) bsum[w] = part;
    __syncthreads();
    if (threadIdx.x == 0) {
        float s = bsum[0] + bsum[1] + bsum[2] + bsum[3];
        unsafeAtomicAdd(out, 0.5f * s / ((float)BC * (float)BC));
    }
}

extern "C" void kernel_launch(void* const* d_in, const int* in_sizes, int n_in,
                              void* d_out, int out_size, void* d_ws, size_t ws_size,
                              hipStream_t stream) {
    const float* hc   = (const float*)d_in[0];  // hidden_current  (4096,768)
    const float* hp   = (const float*)d_in[1];  // hidden_previous (8192,768)
    const int*   labp = (const int*)d_in[3];    // labels_previous (8192,)
    float* out = (float*)d_out;

    // workspace layout (~38 MB)
    unsigned short* hpnb = (unsigned short*)d_ws;          // BP*D bf16 (pre-swizzled)
    float* hcn  = (float*)(hpnb + (size_t)BP * D);         // BC*D f32
    float* sq   = hcn + (size_t)BC * D;                    // BC
    float* candv = sq + BC;                                // BC*NT*TOPK
    int*   candi = (int*)(candv + (size_t)BC * NT * TOPK); // BC*NT*TOPK

    k_norm<<<dim3(BP + BC), dim3(256), 0, stream>>>(hp, hc, hpnb, hcn, sq, out);
    k_simtop<<<dim3(2048), dim3(256), 0, stream>>>(hpnb, candv, candi);
    k_mergeloss<<<dim3(BC / 4), dim3(256), 0, stream>>>(candv, candi, hcn, sq, labp, out);
}